// Round 6
// baseline (908.585 us; speedup 1.0000x reference)
//
#include <hip/hip_runtime.h>
#include <float.h>

// ---------------------------------------------------------------------------
// NonOverlappingFlatVQVAE forward, MI355X (gfx950).
// f32 GEMM pipeline (verified R1) + two-stage VQ:
//   stage 1: bf16x2 MFMA approximate distance scan, top-2 codes per slot
//            (16 slots -> 32 candidates/token). Only needs to contain the
//            true argmin; numeric slop tolerated.
//   stage 2: exact f64 rescoring of the candidates -> true argmin + exact
//            commitment distance (diff). Immune to cnorm/dot f32 error,
//            which R4/R5's identical absmax=1824 isolated as the flip source.
// Workspace NEED = 52,199,424 B (< 64 MiB); f32-scan fallback below that.
// Harness reads d_out as f32 -> idx written as float values.
// ---------------------------------------------------------------------------

#define TOK   8192
#define CBK   8192
#define CBD   512

typedef short  short8v __attribute__((ext_vector_type(8)));
typedef float  f32x4   __attribute__((ext_vector_type(4)));

// ============================ f32 GEMM (verified) ===========================
#define BM  64
#define BN  64
#define BKT 16
#define LDP 68

template<int AMODE, int STMODE, bool RELU>
__global__ __launch_bounds__(256)
void gemm_f32(const float* __restrict__ A, const float* __restrict__ Bw,
              const float* __restrict__ bias, float* __restrict__ C,
              const float* __restrict__ rowidx, int M, int N, int K)
{
    __shared__ __align__(16) float As[BKT][LDP];
    __shared__ __align__(16) float Bs[BKT][LDP];

    const int tid = threadIdx.x;
    const int tx  = tid & 15;
    const int ty  = tid >> 4;
    const int m0  = blockIdx.x * BM;
    const int n0  = blockIdx.y * BN;
    const int ml  = tid & 63;
    const int kl  = (tid >> 6) << 2;

    int arow = m0 + ml;
    size_t abase = 0;
    if constexpr (AMODE == 1) {
        const int m = m0 + ml;
        const int b = m >> 8, i = (m >> 4) & 15, j = m & 15;
        abase = (size_t)b * 196608 + i * 4096 + j * 16;
    } else if constexpr (AMODE == 2) {
        arow = (int)rowidx[m0 + ml];
    }

    float acc[4][4] = {};

    for (int k0 = 0; k0 < K; k0 += BKT) {
        float4 av, bv;
        {
            const int k = k0 + kl;
            if constexpr (AMODE == 1) {
                const int c = k >> 8, p = (k >> 4) & 15, q = k & 15;
                av = *(const float4*)(A + abase + (size_t)c * 65536 + p * 256 + q);
            } else {
                av = *(const float4*)(A + (size_t)arow * K + k);
            }
            bv = *(const float4*)(Bw + (size_t)(n0 + ml) * K + k);
        }
        As[kl+0][ml] = av.x; As[kl+1][ml] = av.y; As[kl+2][ml] = av.z; As[kl+3][ml] = av.w;
        Bs[kl+0][ml] = bv.x; Bs[kl+1][ml] = bv.y; Bs[kl+2][ml] = bv.z; Bs[kl+3][ml] = bv.w;
        __syncthreads();

        #pragma unroll
        for (int kk = 0; kk < BKT; ++kk) {
            const float4 a4 = *(const float4*)&As[kk][ty << 2];
            const float4 b4 = *(const float4*)&Bs[kk][tx << 2];
            const float aa[4] = {a4.x, a4.y, a4.z, a4.w};
            const float bb[4] = {b4.x, b4.y, b4.z, b4.w};
            #pragma unroll
            for (int i = 0; i < 4; ++i)
                #pragma unroll
                for (int j = 0; j < 4; ++j)
                    acc[i][j] = fmaf(aa[i], bb[j], acc[i][j]);
        }
        __syncthreads();
    }

    #pragma unroll
    for (int i = 0; i < 4; ++i) {
        const int m = m0 + (ty << 2) + i;
        const int n = n0 + (tx << 2);
        float4 v;
        float* vp = (float*)&v;
        if constexpr (STMODE == 0) {
            #pragma unroll
            for (int j = 0; j < 4; ++j) {
                float t = acc[i][j] + bias[n + j];
                if constexpr (RELU) t = fmaxf(t, 0.f);
                vp[j] = t;
            }
            *(float4*)(C + (size_t)m * N + n) = v;
        } else {
            const int o = n >> 8, p = (n >> 4) & 15, q = n & 15;
            const int b = m >> 8, ii = (m >> 4) & 15, jj = m & 15;
            const float bo = bias[o];
            #pragma unroll
            for (int j = 0; j < 4; ++j) vp[j] = acc[i][j] + bo;
            *(float4*)(C + (size_t)(b * 3 + o) * 65536 + (ii * 16 + p) * 256 + jj * 16 + q) = v;
        }
    }
}

// ============================ small helpers ================================
// |c_k|^2 with f64 accumulation (stage-1 ranking only; stage-2 is exact).
__global__ __launch_bounds__(256)
void cb_norm(const float* __restrict__ cb, float* __restrict__ cnorm)
{
    const int row  = blockIdx.x * 4 + (threadIdx.x >> 6);
    const int lane = threadIdx.x & 63;
    const float4* p = (const float4*)(cb + (size_t)row * CBD + lane * 8);
    const float4 a = p[0], b = p[1];
    double s = (double)a.x*a.x + (double)a.y*a.y + (double)a.z*a.z + (double)a.w*a.w
             + (double)b.x*b.x + (double)b.y*b.y + (double)b.z*b.z + (double)b.w*b.w;
    #pragma unroll
    for (int off = 32; off >= 1; off >>= 1) s += __shfl_down(s, off);
    if (lane == 0) cnorm[row] = (float)s;
}

__device__ __forceinline__ unsigned short f2bf_rtne(float x) {
    unsigned u = __float_as_uint(x);
    unsigned r = u + 0x7fffu + ((u >> 16) & 1u);
    return (unsigned short)(r >> 16);
}

// f32 -> bf16 hi + bf16 lo(residual)
__global__ __launch_bounds__(256)
void split_bf16_2(const float* __restrict__ src, unsigned short* __restrict__ hi,
                  unsigned short* __restrict__ lo)
{
    const size_t i8 = (size_t)blockIdx.x * 256 + threadIdx.x;
    const float4 a = *(const float4*)(src + i8 * 8);
    const float4 b = *(const float4*)(src + i8 * 8 + 4);
    const float xs[8] = {a.x, a.y, a.z, a.w, b.x, b.y, b.z, b.w};
    union { unsigned short u[8]; short8v v; } H, L;
    #pragma unroll
    for (int j = 0; j < 8; ++j) {
        const unsigned short h = f2bf_rtne(xs[j]);
        H.u[j] = h;
        const float hf = __uint_as_float(((unsigned)h) << 16);
        L.u[j] = f2bf_rtne(xs[j] - hf);
    }
    *(short8v*)(hi + i8 * 8) = H.v;
    *(short8v*)(lo + i8 * 8) = L.v;
}

// ================= stage 1: bf16x2 MFMA scan, top-2 per slot ===============
// Block: 256 thr = 4 waves (2x2), tile 128 tok x 128 codes, K-step 64.
// LDS: Az[2]+Bc[2] (h,l) 16KB each = 64KB. 16B-chunk XOR swizzle c^(r&7),
// applied on write-address-gen and read identically (rule 21).
// dot ~ hh + hl + lh (ll term ~2^-18 rel, omitted; stage 2 re-verifies).
#define VBM 128
#define VBN 128
#define VBK 64
#define NSY 8
#define CPB (CBK / NSY)   // 1024 codes per y-block
#define NCAND_MFMA 32     // 8 y * 2 wc slots * top-2

__global__ __launch_bounds__(256)
void vq_mfma2(const unsigned short* __restrict__ zh, const unsigned short* __restrict__ zl,
              const unsigned short* __restrict__ ch, const unsigned short* __restrict__ cl,
              const float* __restrict__ cnorm, int* __restrict__ cand)
{
    __shared__ __align__(16) unsigned short Az[2][VBM * VBK];
    __shared__ __align__(16) unsigned short Bc[2][VBM * VBK];

    const int tid  = threadIdx.x;
    const int lane = tid & 63;
    const int wid  = tid >> 6;
    const int wr   = wid >> 1;        // token half
    const int wc   = wid & 1;         // code half
    const int m0   = blockIdx.x * VBM;
    const int l15  = lane & 15;
    const int l4   = lane >> 4;

    const unsigned short* const asrc[2] = {zh, zl};
    const unsigned short* const bsrc[2] = {ch, cl};

    float r1[16], r2[16];
    int   i1[16], i2[16];
    #pragma unroll
    for (int r = 0; r < 16; ++r) { r1[r] = FLT_MAX; r2[r] = FLT_MAX; i1[r] = 0; i2[r] = 0; }

    for (int chk = 0; chk < CPB / VBN; ++chk) {
        const int c0 = blockIdx.y * CPB + chk * VBN;

        f32x4 acc[4][4];
        #pragma unroll
        for (int mi = 0; mi < 4; ++mi)
            #pragma unroll
            for (int nj = 0; nj < 4; ++nj)
                acc[mi][nj] = (f32x4){0.f, 0.f, 0.f, 0.f};

        for (int k0 = 0; k0 < CBD; k0 += VBK) {
            __syncthreads();
            // stage both splits; LDS phys chunk ci holds logical chunk (ci&7)^(r&7)
            #pragma unroll
            for (int t = 0; t < 2; ++t) {
                #pragma unroll
                for (int it = 0; it < 4; ++it) {
                    const int ci = it * 256 + tid;          // 0..1023
                    const int r  = ci >> 3, p = ci & 7;
                    const int c  = p ^ (r & 7);
                    *(short8v*)(&Az[t][ci * 8]) =
                        *(const short8v*)(asrc[t] + (size_t)(m0 + r) * CBD + k0 + c * 8);
                    *(short8v*)(&Bc[t][ci * 8]) =
                        *(const short8v*)(bsrc[t] + (size_t)(c0 + r) * CBD + k0 + c * 8);
                }
            }
            __syncthreads();

            #pragma unroll
            for (int ks = 0; ks < 2; ++ks) {
                short8v aFh[4], aFl[4];
                #pragma unroll
                for (int mi = 0; mi < 4; ++mi) {
                    const int r = wr * 64 + mi * 16 + l15;
                    const int off = r * 64 + (((ks * 4 + l4) ^ (r & 7)) << 3);
                    aFh[mi] = *(const short8v*)(&Az[0][off]);
                    aFl[mi] = *(const short8v*)(&Az[1][off]);
                }
                #pragma unroll
                for (int nj = 0; nj < 4; ++nj) {
                    const int rn = wc * 64 + nj * 16 + l15;
                    const int off = rn * 64 + (((ks * 4 + l4) ^ (rn & 7)) << 3);
                    const short8v bh = *(const short8v*)(&Bc[0][off]);
                    const short8v bl = *(const short8v*)(&Bc[1][off]);
                    #pragma unroll
                    for (int mi = 0; mi < 4; ++mi) {
                        acc[mi][nj] = __builtin_amdgcn_mfma_f32_16x16x32_bf16(aFh[mi], bh, acc[mi][nj], 0, 0, 0);
                        acc[mi][nj] = __builtin_amdgcn_mfma_f32_16x16x32_bf16(aFh[mi], bl, acc[mi][nj], 0, 0, 0);
                        acc[mi][nj] = __builtin_amdgcn_mfma_f32_16x16x32_bf16(aFl[mi], bh, acc[mi][nj], 0, 0, 0);
                    }
                }
            }
        }

        // epilogue: dist = |c|^2 - 2*dot ; top-2 update per token row
        #pragma unroll
        for (int nj = 0; nj < 4; ++nj) {
            const int code = c0 + wc * 64 + nj * 16 + l15;
            const float cn = cnorm[code];
            #pragma unroll
            for (int mi = 0; mi < 4; ++mi) {
                #pragma unroll
                for (int i = 0; i < 4; ++i) {
                    const float d = cn - 2.0f * acc[mi][nj][i];
                    const int rr = mi * 4 + i;
                    if (d < r1[rr]) { r2[rr] = r1[rr]; i2[rr] = i1[rr]; r1[rr] = d; i1[rr] = code; }
                    else if (d < r2[rr]) { r2[rr] = d; i2[rr] = code; }
                }
            }
        }
    }

    // merge top-2 across the 16 l15 lanes sharing each token row
    #pragma unroll
    for (int r = 0; r < 16; ++r) {
        float a1 = r1[r], a2 = r2[r];
        int   x1 = i1[r], x2 = i2[r];
        #pragma unroll
        for (int off = 1; off < 16; off <<= 1) {
            const float b1 = __shfl_xor(a1, off), b2 = __shfl_xor(a2, off);
            const int   y1 = __shfl_xor(x1, off), y2 = __shfl_xor(x2, off);
            if (b1 < a1) {
                const float n2 = (a1 < b2) ? a1 : b2;
                const int   m2 = (a1 < b2) ? x1 : y2;
                a2 = n2; x2 = m2; a1 = b1; x1 = y1;
            } else {
                if (b1 < a2) { a2 = b1; x2 = y1; }
            }
        }
        r1[r] = a1; i1[r] = x1; r2[r] = a2; i2[r] = x2;
    }
    if (l15 == 0) {
        const int slot = blockIdx.y * 2 + wc;          // 0..15
        #pragma unroll
        for (int mi = 0; mi < 4; ++mi)
            #pragma unroll
            for (int i = 0; i < 4; ++i) {
                const int tok = m0 + wr * 64 + mi * 16 + l4 * 4 + i;
                cand[(slot * 2 + 0) * TOK + tok] = i1[mi * 4 + i];
                cand[(slot * 2 + 1) * TOK + tok] = i2[mi * 4 + i];
            }
    }
}

// ================== fallback stage 1: f32 scan, top-2 ======================
#define NSPLIT 4
#define CPS (CBK / NSPLIT)
#define NCAND_F32 8

__global__ __launch_bounds__(256)
void vq_argmin(const float* __restrict__ z, const float* __restrict__ cb,
               const float* __restrict__ cnorm, int* __restrict__ cand)
{
    __shared__ __align__(16) float As[BKT][LDP];
    __shared__ __align__(16) float Bs[BKT][LDP];
    __shared__ float rv1[BM][16], rv2[BM][16];
    __shared__ int   ri1[BM][16], ri2[BM][16];

    const int tid = threadIdx.x;
    const int tx  = tid & 15, ty = tid >> 4;
    const int m0  = blockIdx.x * BM;
    const int c0  = blockIdx.y * CPS;
    const int ml  = tid & 63;
    const int kl  = (tid >> 6) << 2;

    float r1[4] = {FLT_MAX, FLT_MAX, FLT_MAX, FLT_MAX};
    float r2[4] = {FLT_MAX, FLT_MAX, FLT_MAX, FLT_MAX};
    int   i1[4] = {0,0,0,0}, i2[4] = {0,0,0,0};

    for (int ct = 0; ct < CPS; ct += BN) {
        float dot[4][4] = {};
        for (int k0 = 0; k0 < CBD; k0 += BKT) {
            const float4 av = *(const float4*)(z  + (size_t)(m0 + ml) * CBD + k0 + kl);
            const float4 bv = *(const float4*)(cb + (size_t)(c0 + ct + ml) * CBD + k0 + kl);
            As[kl+0][ml] = av.x; As[kl+1][ml] = av.y; As[kl+2][ml] = av.z; As[kl+3][ml] = av.w;
            Bs[kl+0][ml] = bv.x; Bs[kl+1][ml] = bv.y; Bs[kl+2][ml] = bv.z; Bs[kl+3][ml] = bv.w;
            __syncthreads();
            #pragma unroll
            for (int kk = 0; kk < BKT; ++kk) {
                const float4 a4 = *(const float4*)&As[kk][ty << 2];
                const float4 b4 = *(const float4*)&Bs[kk][tx << 2];
                const float aa[4] = {a4.x, a4.y, a4.z, a4.w};
                const float bb[4] = {b4.x, b4.y, b4.z, b4.w};
                #pragma unroll
                for (int i = 0; i < 4; ++i)
                    #pragma unroll
                    for (int j = 0; j < 4; ++j)
                        dot[i][j] = fmaf(aa[i], bb[j], dot[i][j]);
            }
            __syncthreads();
        }
        const int cbase = c0 + ct + (tx << 2);
        const float4 cn4 = *(const float4*)(cnorm + cbase);
        const float cn[4] = {cn4.x, cn4.y, cn4.z, cn4.w};
        #pragma unroll
        for (int j = 0; j < 4; ++j)
            #pragma unroll
            for (int i = 0; i < 4; ++i) {
                const float s = cn[j] - 2.f * dot[i][j];
                if (s < r1[i]) { r2[i]=r1[i]; i2[i]=i1[i]; r1[i]=s; i1[i]=cbase+j; }
                else if (s < r2[i]) { r2[i]=s; i2[i]=cbase+j; }
            }
    }

    #pragma unroll
    for (int i = 0; i < 4; ++i) {
        rv1[(ty << 2) + i][tx] = r1[i]; ri1[(ty << 2) + i][tx] = i1[i];
        rv2[(ty << 2) + i][tx] = r2[i]; ri2[(ty << 2) + i][tx] = i2[i];
    }
    __syncthreads();
    if (tid < BM) {
        float a1 = rv1[tid][0], a2 = rv2[tid][0];
        int   x1 = ri1[tid][0], x2 = ri2[tid][0];
        #pragma unroll
        for (int t = 1; t < 16; ++t) {
            const float b1 = rv1[tid][t], b2 = rv2[tid][t];
            const int   y1 = ri1[tid][t], y2 = ri2[tid][t];
            if (b1 < a1) {
                const float n2 = (a1 < b2) ? a1 : b2;
                const int   m2 = (a1 < b2) ? x1 : y2;
                a2 = n2; x2 = m2; a1 = b1; x1 = y1;
            } else if (b1 < a2) { a2 = b1; x2 = y1; }
        }
        const int tok = m0 + tid;
        cand[(blockIdx.y * 2 + 0) * TOK + tok] = x1;
        cand[(blockIdx.y * 2 + 1) * TOK + tok] = x2;
    }
}

// ============ stage 2: exact f64 rescore of candidates + diff ==============
// One 64-lane wave per token; d = sum_k (cb[c][k]-z[k])^2 in f64.
__global__ __launch_bounds__(256)
void exact_select(const float* __restrict__ z, const float* __restrict__ cb,
                  const int* __restrict__ cand, int ncand,
                  float* __restrict__ idx_out, float* __restrict__ diffp)
{
    const int t    = blockIdx.x * 4 + (threadIdx.x >> 6);
    const int lane = threadIdx.x & 63;

    // this token's z slice (8 elems) as f64
    const float4 za = *(const float4*)(z + (size_t)t * CBD + lane * 8);
    const float4 zb = *(const float4*)(z + (size_t)t * CBD + lane * 8 + 4);
    const double zd[8] = {za.x, za.y, za.z, za.w, zb.x, zb.y, zb.z, zb.w};

    double bestd = DBL_MAX;
    int    besti = 0x7fffffff;
    for (int c = 0; c < ncand; ++c) {
        const int code = cand[c * TOK + t];
        const float4 ca = *(const float4*)(cb + (size_t)code * CBD + lane * 8);
        const float4 cbv = *(const float4*)(cb + (size_t)code * CBD + lane * 8 + 4);
        const double cd[8] = {ca.x, ca.y, ca.z, ca.w, cbv.x, cbv.y, cbv.z, cbv.w};
        double s = 0.0;
        #pragma unroll
        for (int j = 0; j < 8; ++j) { const double d = cd[j] - zd[j]; s = fma(d, d, s); }
        #pragma unroll
        for (int off = 32; off >= 1; off >>= 1) s += __shfl_down(s, off);
        s = __shfl(s, 0);   // broadcast so all lanes agree
        if (s < bestd || (s == bestd && code < besti)) { bestd = s; besti = code; }
    }
    if (lane == 0) {
        idx_out[t] = (float)besti;
        atomicAdd(diffp, (float)(bestd * (1.0 / ((double)TOK * CBD))));
    }
}

// up_w [C=256, 768] -> upT [768][256]
__global__ __launch_bounds__(256)
void transpose_upw(const float* __restrict__ up_w, float* __restrict__ upT)
{
    const int id = blockIdx.x * 256 + threadIdx.x;
    const int n = id >> 8, c = id & 255;
    upT[id] = up_w[c * 768 + n];
}

// ---------------------------------------------------------------------------
extern "C" void kernel_launch(void* const* d_in, const int* in_sizes, int n_in,
                              void* d_out, int out_size, void* d_ws, size_t ws_size,
                              hipStream_t stream)
{
    const float* x        = (const float*)d_in[0];
    const float* pe_w     = (const float*)d_in[1];
    const float* pe_b     = (const float*)d_in[2];
    const float* mix1_w   = (const float*)d_in[3];
    const float* mix1_b   = (const float*)d_in[4];
    const float* mix2_w   = (const float*)d_in[5];
    const float* mix2_b   = (const float*)d_in[6];
    const float* qc_w     = (const float*)d_in[7];
    const float* qc_b     = (const float*)d_in[8];
    const float* codebook = (const float*)d_in[9];
    const float* dpre1_w  = (const float*)d_in[10];
    const float* dpre1_b  = (const float*)d_in[11];
    const float* dpre2_w  = (const float*)d_in[12];
    const float* dpre2_b  = (const float*)d_in[13];
    const float* up_w     = (const float*)d_in[14];
    const float* up_b     = (const float*)d_in[15];

    float* ws = (float*)d_ws;
    // layout (float offsets)
    float* h1    = ws;                      // 2,097,152 (8 MB)
    float* h2    = ws + 2097152;            // 2,097,152 (8 MB)
    float* z     = ws + 4194304;            // 4,194,304 (16 MB)
    float* upT   = ws + 8388608;            //   196,608
    float* cnorm = ws + 8585216;            //     8,192
    int*   cand  = (int*)(ws + 8593408);    //   262,144 ints (1 MB)
    unsigned short* cbh = (unsigned short*)(ws + 8855552);   // 8 MB
    unsigned short* cbl = cbh + 4194304;                     // 8 MB
    // z splits overlay h1/h2 (dead between encoder and decoder)
    unsigned short* zh  = (unsigned short*)h1;
    unsigned short* zl  = (unsigned short*)h2;
    const size_t NEED  = 52199424;   // through cbl
    // fallback needs only through cand: 35,422,208 B

    float* dec     = (float*)d_out;
    float* diffp   = dec + 6291456;
    float* idx_out = (float*)d_out + 6291457;

    const bool use_mfma = (ws_size >= NEED);

    transpose_upw<<<768, 256, 0, stream>>>(up_w, upT);
    cb_norm<<<CBK / 4, 256, 0, stream>>>(codebook, cnorm);
    if (use_mfma)
        split_bf16_2<<<2048, 256, 0, stream>>>(codebook, cbh, cbl);

    // encoder (f32, verified)
    gemm_f32<1, 0, true ><<<dim3(TOK/BM, 256/BN), 256, 0, stream>>>(x,  pe_w,   pe_b,   h1, nullptr, TOK, 256, 768);
    gemm_f32<0, 0, true ><<<dim3(TOK/BM, 256/BN), 256, 0, stream>>>(h1, mix1_w, mix1_b, h2, nullptr, TOK, 256, 256);
    gemm_f32<0, 0, false><<<dim3(TOK/BM, 256/BN), 256, 0, stream>>>(h2, mix2_w, mix2_b, h1, nullptr, TOK, 256, 256);
    gemm_f32<0, 0, false><<<dim3(TOK/BM, 512/BN), 256, 0, stream>>>(h1, qc_w,   qc_b,   z,  nullptr, TOK, 512, 256);

    // stage 1: candidate generation
    int ncand;
    if (use_mfma) {
        split_bf16_2<<<2048, 256, 0, stream>>>(z, zh, zl);
        vq_mfma2<<<dim3(TOK/VBM, NSY), 256, 0, stream>>>(zh, zl, cbh, cbl, cnorm, cand);
        ncand = NCAND_MFMA;
    } else {
        vq_argmin<<<dim3(TOK/BM, NSPLIT), 256, 0, stream>>>(z, codebook, cnorm, cand);
        ncand = NCAND_F32;
    }

    // stage 2: exact f64 select + commitment loss
    hipMemsetAsync(diffp, 0, sizeof(float), stream);
    exact_select<<<TOK/4, 256, 0, stream>>>(z, codebook, cand, ncand, idx_out, diffp);

    // decoder (f32, verified; A rows gathered from codebook via float idx)
    gemm_f32<2, 0, true ><<<dim3(TOK/BM, 256/BN), 256, 0, stream>>>(codebook, dpre1_w, dpre1_b, h1, idx_out, TOK, 256, 512);
    gemm_f32<0, 0, true ><<<dim3(TOK/BM, 256/BN), 256, 0, stream>>>(h1, dpre2_w, dpre2_b, h2, nullptr, TOK, 256, 256);
    gemm_f32<0, 1, false><<<dim3(TOK/BM, 768/BN), 256, 0, stream>>>(h2, upT, up_b, dec, nullptr, TOK, 768, 256);
}

// Round 7
// 720.722 us; speedup vs baseline: 1.2607x; 1.2607x over previous
//
#include <hip/hip_runtime.h>
#include <hip/hip_bf16.h>
#include <float.h>

// ---------------------------------------------------------------------------
// NonOverlappingFlatVQVAE forward, MI355X (gfx950). All matmuls on MFMA.
//   encoder GEMMs : bf16x2 split, 4 passes (hh+hl+lh+ll) == exact to 2^-18
//   decoder GEMMs : bf16x2 split, 3 passes (idx-independent, lenient thresh)
//   VQ stage 1    : bf16-hi-only MFMA scan, top-2 per slot (32 cand/token)
//   VQ stage 2    : exact f64 rescore of candidates -> true argmin + diff
// ws layout == 52,199,424 B exactly (proven available in R6).
// Harness reads d_out as f32 -> idx written as float values.
// ---------------------------------------------------------------------------

#define TOK   8192
#define CBK   8192
#define CBD   512

typedef short  short8v __attribute__((ext_vector_type(8)));
typedef float  f32x4   __attribute__((ext_vector_type(4)));

__device__ __forceinline__ unsigned short f2bf(float x) {
    union { __hip_bfloat16 b; unsigned short u; } c;
    c.b = __float2bfloat16(x);
    return c.u;
}
__device__ __forceinline__ float bf2f(unsigned short h) {
    return __uint_as_float((unsigned)h << 16);
}

// ===================== generic MFMA GEMM, inline bf16x2 ====================
// C[M,N] = A[M,K] x Bw[N,K]^T + bias. Tile 128(M) x 64(N), K-step 64,
// 4 waves (2x2). LDS 48KB: Az[2] 16KB(h,l) + Bc[2] 8KB. Swizzle c^(r&7) on
// both write and read (R6-verified conflict-free, SQ_LDS_BANK_CONFLICT=0).
// AMODE: 0 dense, 1 patchify-gather from x[B,3,256,256], 2 row-gather idx.
// STMODE: 0 dense row-major, 1 scatter to dec[B,3,256,256] (bias[n>>8]).
template<int NPASS, int AMODE, int STMODE, bool RELU>
__global__ __launch_bounds__(256)
void gemm_mfma(const float* __restrict__ A, const float* __restrict__ Bw,
               const float* __restrict__ bias, float* __restrict__ C,
               const float* __restrict__ rowidx, int M, int N, int K)
{
    __shared__ __align__(16) unsigned short Az[2][128 * 64];
    __shared__ __align__(16) unsigned short Bc[2][64 * 64];

    const int tid = threadIdx.x, lane = tid & 63, wid = tid >> 6;
    const int wr = wid >> 1, wc = wid & 1;
    const int m0 = blockIdx.x * 128, n0 = blockIdx.y * 64;
    const int l15 = lane & 15, l4 = lane >> 4;

    // per-thread A row bases for staging (row r = it*32 + tid/8)
    size_t abase[4];
    #pragma unroll
    for (int it = 0; it < 4; ++it) {
        const int m = m0 + it * 32 + (tid >> 3);
        if constexpr (AMODE == 1) {
            const int b = m >> 8, i = (m >> 4) & 15, j = m & 15;
            abase[it] = (size_t)b * 196608 + i * 4096 + j * 16;
        } else if constexpr (AMODE == 2) {
            abase[it] = (size_t)((int)rowidx[m]) * K;
        } else {
            abase[it] = (size_t)m * K;
        }
    }

    f32x4 acc[4][2];
    #pragma unroll
    for (int mi = 0; mi < 4; ++mi)
        #pragma unroll
        for (int nj = 0; nj < 2; ++nj)
            acc[mi][nj] = (f32x4){0.f, 0.f, 0.f, 0.f};

    for (int k0 = 0; k0 < K; k0 += 64) {
        __syncthreads();
        // ---- stage A (128x64 f32 -> h,l) ----
        #pragma unroll
        for (int it = 0; it < 4; ++it) {
            const int ci = it * 256 + tid;
            const int r = ci >> 3, cb8 = ci & 7;
            const int kk = k0 + cb8 * 8;
            const float* src;
            if constexpr (AMODE == 1) {
                const int c = kk >> 8, p = (kk >> 4) & 15, q = kk & 15;
                src = A + abase[it] + (size_t)c * 65536 + p * 256 + q;
            } else {
                src = A + abase[it] + kk;
            }
            const float4 f0 = *(const float4*)src;
            const float4 f1 = *(const float4*)(src + 4);
            const float fs[8] = {f0.x, f0.y, f0.z, f0.w, f1.x, f1.y, f1.z, f1.w};
            union { unsigned short u[8]; short8v v; } H, L;
            #pragma unroll
            for (int j = 0; j < 8; ++j) {
                const unsigned short h = f2bf(fs[j]);
                H.u[j] = h;
                L.u[j] = f2bf(fs[j] - bf2f(h));
            }
            const int off = r * 64 + ((cb8 ^ (r & 7)) << 3);
            *(short8v*)(&Az[0][off]) = H.v;
            *(short8v*)(&Az[1][off]) = L.v;
        }
        // ---- stage B (64x64 f32 -> h,l) ----
        #pragma unroll
        for (int it = 0; it < 2; ++it) {
            const int ci = it * 256 + tid;
            const int r = ci >> 3, cb8 = ci & 7;
            const float* src = Bw + (size_t)(n0 + r) * K + k0 + cb8 * 8;
            const float4 f0 = *(const float4*)src;
            const float4 f1 = *(const float4*)(src + 4);
            const float fs[8] = {f0.x, f0.y, f0.z, f0.w, f1.x, f1.y, f1.z, f1.w};
            union { unsigned short u[8]; short8v v; } H, L;
            #pragma unroll
            for (int j = 0; j < 8; ++j) {
                const unsigned short h = f2bf(fs[j]);
                H.u[j] = h;
                L.u[j] = f2bf(fs[j] - bf2f(h));
            }
            const int off = r * 64 + ((cb8 ^ (r & 7)) << 3);
            *(short8v*)(&Bc[0][off]) = H.v;
            *(short8v*)(&Bc[1][off]) = L.v;
        }
        __syncthreads();

        #pragma unroll
        for (int ks = 0; ks < 2; ++ks) {
            short8v aFh[4], aFl[4];
            #pragma unroll
            for (int mi = 0; mi < 4; ++mi) {
                const int r = wr * 64 + mi * 16 + l15;
                const int off = r * 64 + (((ks * 4 + l4) ^ (r & 7)) << 3);
                aFh[mi] = *(const short8v*)(&Az[0][off]);
                aFl[mi] = *(const short8v*)(&Az[1][off]);
            }
            #pragma unroll
            for (int nj = 0; nj < 2; ++nj) {
                const int rn = wc * 32 + nj * 16 + l15;
                const int off = rn * 64 + (((ks * 4 + l4) ^ (rn & 7)) << 3);
                const short8v bh = *(const short8v*)(&Bc[0][off]);
                const short8v bl = *(const short8v*)(&Bc[1][off]);
                #pragma unroll
                for (int mi = 0; mi < 4; ++mi) {
                    acc[mi][nj] = __builtin_amdgcn_mfma_f32_16x16x32_bf16(aFh[mi], bh, acc[mi][nj], 0, 0, 0);
                    acc[mi][nj] = __builtin_amdgcn_mfma_f32_16x16x32_bf16(aFh[mi], bl, acc[mi][nj], 0, 0, 0);
                    acc[mi][nj] = __builtin_amdgcn_mfma_f32_16x16x32_bf16(aFl[mi], bh, acc[mi][nj], 0, 0, 0);
                    if constexpr (NPASS == 4)
                        acc[mi][nj] = __builtin_amdgcn_mfma_f32_16x16x32_bf16(aFl[mi], bl, acc[mi][nj], 0, 0, 0);
                }
            }
        }
    }

    // epilogue: C/D layout col=lane&15 (n), row=(lane>>4)*4+i (m)  [R6-verified]
    #pragma unroll
    for (int nj = 0; nj < 2; ++nj) {
        const int n = n0 + wc * 32 + nj * 16 + l15;
        const float bv = (STMODE == 0) ? bias[n] : bias[n >> 8];
        #pragma unroll
        for (int mi = 0; mi < 4; ++mi) {
            #pragma unroll
            for (int i = 0; i < 4; ++i) {
                const int m = m0 + wr * 64 + mi * 16 + l4 * 4 + i;
                float v = acc[mi][nj][i] + bv;
                if constexpr (RELU) v = fmaxf(v, 0.f);
                if constexpr (STMODE == 0) {
                    C[(size_t)m * N + n] = v;
                } else {
                    const int o = n >> 8, p = (n >> 4) & 15, q = n & 15;
                    const int b = m >> 8, ii = (m >> 4) & 15, jj = m & 15;
                    C[((size_t)(b * 3 + o) * 256 + ii * 16 + p) * 256 + jj * 16 + q] = v;
                }
            }
        }
    }
}

// ============================ small helpers ================================
__global__ __launch_bounds__(256)
void cb_norm(const float* __restrict__ cb, float* __restrict__ cnorm)
{
    const int row  = blockIdx.x * 4 + (threadIdx.x >> 6);
    const int lane = threadIdx.x & 63;
    const float4* p = (const float4*)(cb + (size_t)row * CBD + lane * 8);
    const float4 a = p[0], b = p[1];
    double s = (double)a.x*a.x + (double)a.y*a.y + (double)a.z*a.z + (double)a.w*a.w
             + (double)b.x*b.x + (double)b.y*b.y + (double)b.z*b.z + (double)b.w*b.w;
    #pragma unroll
    for (int off = 32; off >= 1; off >>= 1) s += __shfl_down(s, off);
    if (lane == 0) cnorm[row] = (float)s;
}

// f32 -> bf16 hi mirror (stage-1 inputs)
__global__ __launch_bounds__(256)
void split_bf16_h(const float* __restrict__ src, unsigned short* __restrict__ hi)
{
    const size_t i8 = (size_t)blockIdx.x * 256 + threadIdx.x;
    const float4 a = *(const float4*)(src + i8 * 8);
    const float4 b = *(const float4*)(src + i8 * 8 + 4);
    const float xs[8] = {a.x, a.y, a.z, a.w, b.x, b.y, b.z, b.w};
    union { unsigned short u[8]; short8v v; } H;
    #pragma unroll
    for (int j = 0; j < 8; ++j) H.u[j] = f2bf(xs[j]);
    *(short8v*)(hi + i8 * 8) = H.v;
}

// ================= stage 1: bf16-hi MFMA scan, top-2 per slot ==============
// 256 thr = 4 waves (2x2), tile 128 tok x 128 codes, K-step 64. LDS 32KB.
// dist err ~1e-3 << in-slot top-2 gaps ~5 -> containment safe (R4-calibrated).
#define NSY 8
#define CPB (CBK / NSY)   // 1024 codes per y-block
#define NCAND 32          // 16 slots x top-2

__global__ __launch_bounds__(256)
void vq_mfma1(const unsigned short* __restrict__ zh, const unsigned short* __restrict__ cbh,
              const float* __restrict__ cnorm, int* __restrict__ cand)
{
    __shared__ __align__(16) unsigned short Az[128 * 64];
    __shared__ __align__(16) unsigned short Bc[128 * 64];

    const int tid = threadIdx.x, lane = tid & 63, wid = tid >> 6;
    const int wr = wid >> 1, wc = wid & 1;
    const int m0 = blockIdx.x * 128;
    const int l15 = lane & 15, l4 = lane >> 4;

    float r1[16], r2[16];
    int   i1[16], i2[16];
    #pragma unroll
    for (int r = 0; r < 16; ++r) { r1[r] = FLT_MAX; r2[r] = FLT_MAX; i1[r] = 0; i2[r] = 0; }

    for (int chk = 0; chk < CPB / 128; ++chk) {
        const int c0 = blockIdx.y * CPB + chk * 128;

        f32x4 acc[4][4];
        #pragma unroll
        for (int mi = 0; mi < 4; ++mi)
            #pragma unroll
            for (int nj = 0; nj < 4; ++nj)
                acc[mi][nj] = (f32x4){0.f, 0.f, 0.f, 0.f};

        for (int k0 = 0; k0 < CBD; k0 += 64) {
            __syncthreads();
            #pragma unroll
            for (int it = 0; it < 4; ++it) {
                const int ci = it * 256 + tid;
                const int r = ci >> 3, cb8 = ci & 7;
                const int off = r * 64 + ((cb8 ^ (r & 7)) << 3);
                *(short8v*)(&Az[off]) =
                    *(const short8v*)(zh + (size_t)(m0 + r) * CBD + k0 + cb8 * 8);
                *(short8v*)(&Bc[off]) =
                    *(const short8v*)(cbh + (size_t)(c0 + r) * CBD + k0 + cb8 * 8);
            }
            __syncthreads();

            #pragma unroll
            for (int ks = 0; ks < 2; ++ks) {
                short8v aF[4];
                #pragma unroll
                for (int mi = 0; mi < 4; ++mi) {
                    const int r = wr * 64 + mi * 16 + l15;
                    aF[mi] = *(const short8v*)(&Az[r * 64 + (((ks * 4 + l4) ^ (r & 7)) << 3)]);
                }
                #pragma unroll
                for (int nj = 0; nj < 4; ++nj) {
                    const int rn = wc * 64 + nj * 16 + l15;
                    const short8v bF = *(const short8v*)(&Bc[rn * 64 + (((ks * 4 + l4) ^ (rn & 7)) << 3)]);
                    #pragma unroll
                    for (int mi = 0; mi < 4; ++mi)
                        acc[mi][nj] = __builtin_amdgcn_mfma_f32_16x16x32_bf16(aF[mi], bF, acc[mi][nj], 0, 0, 0);
                }
            }
        }

        // dist = |c|^2 - 2*dot ; top-2 update per token row
        #pragma unroll
        for (int nj = 0; nj < 4; ++nj) {
            const int code = c0 + wc * 64 + nj * 16 + l15;
            const float cn = cnorm[code];
            #pragma unroll
            for (int mi = 0; mi < 4; ++mi) {
                #pragma unroll
                for (int i = 0; i < 4; ++i) {
                    const float d = cn - 2.0f * acc[mi][nj][i];
                    const int rr = mi * 4 + i;
                    if (d < r1[rr]) { r2[rr] = r1[rr]; i2[rr] = i1[rr]; r1[rr] = d; i1[rr] = code; }
                    else if (d < r2[rr]) { r2[rr] = d; i2[rr] = code; }
                }
            }
        }
    }

    // merge top-2 across the 16 l15 lanes sharing each token row
    #pragma unroll
    for (int r = 0; r < 16; ++r) {
        float a1 = r1[r], a2 = r2[r];
        int   x1 = i1[r], x2 = i2[r];
        #pragma unroll
        for (int off = 1; off < 16; off <<= 1) {
            const float b1 = __shfl_xor(a1, off), b2 = __shfl_xor(a2, off);
            const int   y1 = __shfl_xor(x1, off), y2 = __shfl_xor(x2, off);
            if (b1 < a1) {
                const float n2 = (a1 < b2) ? a1 : b2;
                const int   m2 = (a1 < b2) ? x1 : y2;
                a2 = n2; x2 = m2; a1 = b1; x1 = y1;
            } else {
                if (b1 < a2) { a2 = b1; x2 = y1; }
            }
        }
        r1[r] = a1; i1[r] = x1; r2[r] = a2; i2[r] = x2;
    }
    if (l15 == 0) {
        const int slot = blockIdx.y * 2 + wc;          // 0..15
        #pragma unroll
        for (int mi = 0; mi < 4; ++mi)
            #pragma unroll
            for (int i = 0; i < 4; ++i) {
                const int tok = m0 + wr * 64 + mi * 16 + l4 * 4 + i;
                cand[(slot * 2 + 0) * TOK + tok] = i1[mi * 4 + i];
                cand[(slot * 2 + 1) * TOK + tok] = i2[mi * 4 + i];
            }
    }
}

// ============ stage 2: exact f64 rescore of candidates + diff ==============
__global__ __launch_bounds__(256)
void exact_select(const float* __restrict__ z, const float* __restrict__ cb,
                  const int* __restrict__ cand, int ncand,
                  float* __restrict__ idx_out, float* __restrict__ diffp)
{
    const int t    = blockIdx.x * 4 + (threadIdx.x >> 6);
    const int lane = threadIdx.x & 63;

    const float4 za = *(const float4*)(z + (size_t)t * CBD + lane * 8);
    const float4 zb = *(const float4*)(z + (size_t)t * CBD + lane * 8 + 4);
    const double zd[8] = {za.x, za.y, za.z, za.w, zb.x, zb.y, zb.z, zb.w};

    double bestd = DBL_MAX;
    int    besti = 0x7fffffff;
    for (int c = 0; c < ncand; ++c) {
        const int code = cand[c * TOK + t];
        const float4 ca  = *(const float4*)(cb + (size_t)code * CBD + lane * 8);
        const float4 cbv = *(const float4*)(cb + (size_t)code * CBD + lane * 8 + 4);
        const double cd[8] = {ca.x, ca.y, ca.z, ca.w, cbv.x, cbv.y, cbv.z, cbv.w};
        double s = 0.0;
        #pragma unroll
        for (int j = 0; j < 8; ++j) { const double d = cd[j] - zd[j]; s = fma(d, d, s); }
        #pragma unroll
        for (int off = 32; off >= 1; off >>= 1) s += __shfl_down(s, off);
        s = __shfl(s, 0);
        if (s < bestd || (s == bestd && code < besti)) { bestd = s; besti = code; }
    }
    if (lane == 0) {
        idx_out[t] = (float)besti;
        atomicAdd(diffp, (float)(bestd * (1.0 / ((double)TOK * CBD))));
    }
}

// up_w [C=256, 768] -> upT [768][256]
__global__ __launch_bounds__(256)
void transpose_upw(const float* __restrict__ up_w, float* __restrict__ upT)
{
    const int id = blockIdx.x * 256 + threadIdx.x;
    const int n = id >> 8, c = id & 255;
    upT[id] = up_w[c * 768 + n];
}

// ---------------------------------------------------------------------------
extern "C" void kernel_launch(void* const* d_in, const int* in_sizes, int n_in,
                              void* d_out, int out_size, void* d_ws, size_t ws_size,
                              hipStream_t stream)
{
    const float* x        = (const float*)d_in[0];
    const float* pe_w     = (const float*)d_in[1];
    const float* pe_b     = (const float*)d_in[2];
    const float* mix1_w   = (const float*)d_in[3];
    const float* mix1_b   = (const float*)d_in[4];
    const float* mix2_w   = (const float*)d_in[5];
    const float* mix2_b   = (const float*)d_in[6];
    const float* qc_w     = (const float*)d_in[7];
    const float* qc_b     = (const float*)d_in[8];
    const float* codebook = (const float*)d_in[9];
    const float* dpre1_w  = (const float*)d_in[10];
    const float* dpre1_b  = (const float*)d_in[11];
    const float* dpre2_w  = (const float*)d_in[12];
    const float* dpre2_b  = (const float*)d_in[13];
    const float* up_w     = (const float*)d_in[14];
    const float* up_b     = (const float*)d_in[15];

    float* ws = (float*)d_ws;
    // layout (float offsets); total 13,049,856 floats = 52,199,424 B (== R6 NEED, proven)
    float* h1    = ws;                       // 2,097,152
    float* h2    = ws + 2097152;             // 2,097,152
    float* z     = ws + 4194304;             // 4,194,304
    float* upT   = ws + 8388608;             //   196,608
    float* cnorm = ws + 8585216;             //     8,192
    int*   cand  = (int*)(ws + 8593408);     //   262,144 ints
    unsigned short* zh  = (unsigned short*)(ws + 8855552);   // 4,194,304 ush
    unsigned short* cbh = (unsigned short*)(ws + 10952704);  // 4,194,304 ush

    float* dec     = (float*)d_out;
    float* diffp   = dec + 6291456;
    float* idx_out = (float*)d_out + 6291457;

    // prep
    transpose_upw<<<768, 256, 0, stream>>>(up_w, upT);
    cb_norm<<<CBK / 4, 256, 0, stream>>>(codebook, cnorm);
    split_bf16_h<<<2048, 256, 0, stream>>>(codebook, cbh);

    // encoder (bf16x2, 4 passes == f32-exact to 2^-18)
    gemm_mfma<4, 1, 0, true ><<<dim3(64, 4),  256, 0, stream>>>(x,  pe_w,   pe_b,   h1, nullptr, TOK, 256, 768);
    gemm_mfma<4, 0, 0, true ><<<dim3(64, 4),  256, 0, stream>>>(h1, mix1_w, mix1_b, h2, nullptr, TOK, 256, 256);
    gemm_mfma<4, 0, 0, false><<<dim3(64, 4),  256, 0, stream>>>(h2, mix2_w, mix2_b, h1, nullptr, TOK, 256, 256);
    gemm_mfma<4, 0, 0, false><<<dim3(64, 8),  256, 0, stream>>>(h1, qc_w,   qc_b,   z,  nullptr, TOK, 512, 256);

    // vector quantization: approx scan -> exact rescore
    split_bf16_h<<<2048, 256, 0, stream>>>(z, zh);
    vq_mfma1<<<dim3(TOK / 128, NSY), 256, 0, stream>>>(zh, cbh, cnorm, cand);
    hipMemsetAsync(diffp, 0, sizeof(float), stream);
    exact_select<<<TOK / 4, 256, 0, stream>>>(z, codebook, cand, NCAND, idx_out, diffp);

    // decoder (bf16x2, 3 passes; idx-gather A rows from f32 codebook)
    gemm_mfma<3, 2, 0, true ><<<dim3(64, 4),  256, 0, stream>>>(codebook, dpre1_w, dpre1_b, h1, idx_out, TOK, 256, 512);
    gemm_mfma<3, 0, 0, true ><<<dim3(64, 4),  256, 0, stream>>>(h1, dpre2_w, dpre2_b, h2, nullptr, TOK, 256, 256);
    gemm_mfma<3, 0, 1, false><<<dim3(64, 12), 256, 0, stream>>>(h2, upT, up_b, dec, nullptr, TOK, 768, 256);
}